// Round 2
// baseline (340.661 us; speedup 1.0000x reference)
//
#include <hip/hip_runtime.h>
#include <hip/hip_bf16.h>
#include <math.h>

// Problem constants (match reference)
#define V_SIZE 100000
#define D_DIM  256
#define S_DIM  128
#define H_DIM  512
#define B_SIZE 8192
#define K_NEG  32
#define NR     60000           // NUM_REGULAR
#define NMOD   (V_SIZE - NR)   // 40000 modified words

// MLP tiling: TM=32 divides 40000 and 8192 exactly -> no pad rows.
// LDS 32*516*2 = 33,024 B -> 4 blocks/CU (vs 3 at TM=48); tail finer too.
#define TM     32
#define CBLK   1250            // 40000/32
#define UBLK   256             // 8192/32
// LDS H row stride (shorts). 516: layer-1 b16 writes land 2 lanes/bank
// (free); 1032-B rows keep 8-B alignment for ds_read_b64 in layer 2.
#define HPAD   516

typedef __attribute__((ext_vector_type(8))) short bf16x8;   // 8 bf16 = 4 VGPRs
typedef __attribute__((ext_vector_type(4))) float f32x4;

static __device__ __forceinline__ short f2bf(float f) {
    unsigned u = __builtin_bit_cast(unsigned, f);
    unsigned r = (u + 0x7fffu + ((u >> 16) & 1u)) >> 16;   // RNE
    return (short)r;
}

// ---------------------------------------------------------------------------
// Merged prep: convert_x + gather_xu + all four weight transposes in ONE
// launch. Grid partition is exact (no tails, no pad rows at TM=32):
//   [0, 1280000)            convert_x  (40000*128/4 quads)
//   [1280000, 1542144)      gather_xu  (8192*128/4 quads)
//   [1542144, 1935360)      transposes (393216 elements)
// 1935360 / 256 = 7560 blocks exactly.
// ---------------------------------------------------------------------------
#define N_CONV (NMOD * S_DIM / 4)             // 1,280,000
#define N_XU   (B_SIZE * S_DIM / 4)           //   262,144
#define N_TR   393216

__global__ __launch_bounds__(256) void prep_kernel(
    const float* __restrict__ stoich, const int* __restrict__ pos_u,
    const float* __restrict__ tw1, const float* __restrict__ cw1,
    const float* __restrict__ tw2, const float* __restrict__ cw2,
    short* __restrict__ xbf, short* __restrict__ xu,
    short* __restrict__ W1T_t, short* __restrict__ W1T_c,
    short* __restrict__ W2T_t, short* __restrict__ W2T_c)
{
    int t = blockIdx.x * 256 + threadIdx.x;
    if (t < N_CONV) {
        // Xbf[0..40000*S) = bf16(stoich[NR..NR+NMOD))
        const float4 v = ((const float4*)(stoich + (size_t)NR * S_DIM))[t];
        short4 o;
        o.x = f2bf(v.x); o.y = f2bf(v.y); o.z = f2bf(v.z); o.w = f2bf(v.w);
        ((short4*)xbf)[t] = o;
    } else if (t < N_CONV + N_XU) {
        // Xu[b][:] = bf16(stoich[pos_u[b]][:])
        int t2 = t - N_CONV;
        int b = t2 >> 5, j = t2 & 31;                 // S/4 = 32 chunks per row
        int pu = pos_u[b];
        const float4 v = *(const float4*)(stoich + (size_t)pu * S_DIM + j * 4);
        short4 o;
        o.x = f2bf(v.x); o.y = f2bf(v.y); o.z = f2bf(v.z); o.w = f2bf(v.w);
        ((short4*)xu)[t2] = o;
    } else {
        // fp32 -> bf16 weight transposes, [K][N] -> [N][K]
        int t3 = t - (N_CONV + N_XU);                 // [0, 393216)
        if (t3 < 65536) {            // W1T_t: out[n*128+k] = tw1[k*512+n]
            int n = t3 >> 7, k = t3 & 127;
            W1T_t[t3] = f2bf(tw1[(size_t)k * H_DIM + n]);
        } else if (t3 < 131072) {
            int t4 = t3 - 65536; int n = t4 >> 7, k = t4 & 127;
            W1T_c[t4] = f2bf(cw1[(size_t)k * H_DIM + n]);
        } else if (t3 < 262144) {    // W2T_t: out[n*512+k] = tw2[k*256+n]
            int t4 = t3 - 131072; int n = t4 >> 9, k = t4 & 511;
            W2T_t[t4] = f2bf(tw2[(size_t)k * D_DIM + n]);
        } else if (t3 < N_TR) {
            int t4 = t3 - 262144; int n = t4 >> 9, k = t4 & 511;
            W2T_c[t4] = f2bf(cw2[(size_t)k * D_DIM + n]);
        }
    }
}

// ---------------------------------------------------------------------------
// Fused 2-layer MLP (c-side table + u-side gathered rows in one launch).
// out[M][256] fp32 = relu(A[M][128] @ W1 + b1) @ W2 + b2
// Block = 4 waves, TM=32 rows (2 x 16). Layer 1: wave owns 128 H-cols
// (2 halves of 64). Layer 2: wave owns 64 out-cols; global W2T fragments
// prefetched DEPTH-2 (L2 latency ~250cy > per-ks MFMA issue ~40cy at
// depth 1), LDS A fragments depth-1.
// Verified MFMA layouts (m89/m91): A[m=lane&15][k=q*8+j]; B^T row (lane&15)
// supplies B[k][n=lane&15]; D: col=lane&15, row=q*4+reg.
// ---------------------------------------------------------------------------
__global__ __launch_bounds__(256, 4) void fused_mlp_kernel(
    const short* __restrict__ Xc,  const short* __restrict__ W1c,
    const float* __restrict__ b1c, const short* __restrict__ W2c,
    const float* __restrict__ b2c, float* __restrict__ outc,
    const short* __restrict__ Xu,  const short* __restrict__ W1u,
    const float* __restrict__ b1u, const short* __restrict__ W2u,
    const float* __restrict__ b2u, float* __restrict__ outu)
{
    __shared__ short sH[TM * HPAD];   // 33,024 B -> 4 blocks/CU

    const int blk = blockIdx.x;
    const short *A, *W1T, *W2T; const float *b1, *b2; float* out; int m0;
    if (blk < CBLK) { A = Xc; W1T = W1c; b1 = b1c; W2T = W2c; b2 = b2c;
                      out = outc; m0 = blk * TM; }
    else            { A = Xu; W1T = W1u; b1 = b1u; W2T = W2u; b2 = b2u;
                      out = outu; m0 = (blk - CBLK) * TM; }

    const int lane = threadIdx.x & 63;
    const int wv   = threadIdx.x >> 6;
    const int fr   = lane & 15;
    const int q    = lane >> 4;

    // ---- layer 1 ----
    const short* Ap = A + (size_t)(m0 + fr) * S_DIM + q * 8;
    bf16x8 af[4][2];
    #pragma unroll
    for (int ks = 0; ks < 4; ++ks)
        #pragma unroll
        for (int mi = 0; mi < 2; ++mi)
            af[ks][mi] = *(const bf16x8*)(Ap + mi * 16 * S_DIM + ks * 32);

    #pragma unroll
    for (int half = 0; half < 2; ++half) {
        const int n0h = wv * 128 + half * 64;
        const short* Bp = W1T + (size_t)(n0h + fr) * S_DIM + q * 8;
        f32x4 acc[2][4] = {};
        #pragma unroll
        for (int ks = 0; ks < 4; ++ks) {
            bf16x8 bfr[4];
            #pragma unroll
            for (int ni = 0; ni < 4; ++ni)
                bfr[ni] = *(const bf16x8*)(Bp + ni * 16 * S_DIM + ks * 32);
            #pragma unroll
            for (int mi = 0; mi < 2; ++mi)
                #pragma unroll
                for (int ni = 0; ni < 4; ++ni)
                    acc[mi][ni] = __builtin_amdgcn_mfma_f32_16x16x32_bf16(
                        af[ks][mi], bfr[ni], acc[mi][ni], 0, 0, 0);
        }
        #pragma unroll
        for (int ni = 0; ni < 4; ++ni) {
            int c = n0h + ni * 16 + fr;
            float bv = b1[c];
            #pragma unroll
            for (int mi = 0; mi < 2; ++mi)
                #pragma unroll
                for (int r = 0; r < 4; ++r)
                    sH[(mi * 16 + q * 4 + r) * HPAD + c] =
                        f2bf(fmaxf(acc[mi][ni][r] + bv, 0.f));
        }
    }
    __syncthreads();

    // ---- layer 2: depth-2 global B prefetch, depth-1 LDS A, 16 K-steps ----
    const short* Bp2 = W2T + (size_t)(wv * 64 + fr) * H_DIM + q * 8;
    f32x4 acc2[2][4] = {};
    bf16x8 bA[4], bB[4], bC[4], aA[2], aB[2];

    #define LOAD_B(ks, dst)                                                   \
        _Pragma("unroll")                                                     \
        for (int ni = 0; ni < 4; ++ni)                                        \
            dst[ni] = *(const bf16x8*)(Bp2 + ni * 16 * H_DIM + (ks) * 32);
    #define LOAD_A(ks, dst)                                                   \
        _Pragma("unroll")                                                     \
        for (int mi = 0; mi < 2; ++mi) {                                      \
            const short* hp = &sH[(mi * 16 + fr) * HPAD + (ks) * 32 + q * 8]; \
            short4 lo = *(const short4*)hp;                                   \
            short4 hi = *(const short4*)(hp + 4);                             \
            bf16x8 v;                                                         \
            v[0] = lo.x; v[1] = lo.y; v[2] = lo.z; v[3] = lo.w;               \
            v[4] = hi.x; v[5] = hi.y; v[6] = hi.z; v[7] = hi.w;               \
            dst[mi] = v;                                                      \
        }

    LOAD_B(0, bA);
    LOAD_B(1, bB);
    LOAD_A(0, aA);
    #pragma unroll
    for (int ks = 0; ks < 16; ++ks) {
        if (ks < 14) { LOAD_B(ks + 2, bC); }
        if (ks < 15) { LOAD_A(ks + 1, aB); }
        #pragma unroll
        for (int mi = 0; mi < 2; ++mi)
            #pragma unroll
            for (int ni = 0; ni < 4; ++ni)
                acc2[mi][ni] = __builtin_amdgcn_mfma_f32_16x16x32_bf16(
                    aA[mi], bA[ni], acc2[mi][ni], 0, 0, 0);
        if (ks < 15) {
            #pragma unroll
            for (int i = 0; i < 4; ++i) { bA[i] = bB[i]; bB[i] = bC[i]; }
            #pragma unroll
            for (int i = 0; i < 2; ++i) aA[i] = aB[i];
        }
    }
    #undef LOAD_A
    #undef LOAD_B

    #pragma unroll
    for (int ni = 0; ni < 4; ++ni) {
        int c = wv * 64 + ni * 16 + fr;
        float bv = b2[c];
        #pragma unroll
        for (int mi = 0; mi < 2; ++mi)
            #pragma unroll
            for (int r = 0; r < 4; ++r) {
                int row = m0 + mi * 16 + q * 4 + r;
                out[(size_t)row * D_DIM + c] = acc2[mi][ni][r] + bv;
            }
    }
}

// ---------------------------------------------------------------------------
// Scoring. One block (4 waves) per sample, 16-lane dots (4 rows in flight
// per wave), fast transcendental logsig.
// total_b = 2*( -logsig(clip(eu.ev)) - sum_k logsig(-clip(env_k.eu)) )
// ---------------------------------------------------------------------------
__device__ __forceinline__ float logsig_fast(float x) {
    float t = __expf(-fabsf(x));
    return fminf(x, 0.f) - __logf(1.f + t);
}
__device__ __forceinline__ float clip10(float x) {
    return fminf(fmaxf(x, -10.f), 10.f);
}
__device__ __forceinline__ float dot4(float4 a, float4 b) {
    return a.x * b.x + a.y * b.y + a.z * b.z + a.w * b.w;
}

__global__ __launch_bounds__(256) void score_kernel(
    const int*   __restrict__ pos_u,
    const int*   __restrict__ pos_v,
    const int*   __restrict__ neg_v,
    const float* __restrict__ u_emb,
    const float* __restrict__ v_emb,
    const float* __restrict__ tab_c,   // [NMOD][256] fp32
    const float* __restrict__ Ubuf,    // [B][256] fp32
    float* __restrict__ partials)      // [B]
{
    const int b    = blockIdx.x;
    const int lane = threadIdx.x & 63;
    const int wv   = threadIdx.x >> 6;
    const int g    = lane >> 4;
    const int l    = lane & 15;

    int pu = pos_u[b];
    const float* eup = (pu < NR) ? u_emb + (size_t)pu * D_DIM
                                 : Ubuf  + (size_t)b  * D_DIM;
    float4 eu[4];
    #pragma unroll
    for (int j = 0; j < 4; ++j)
        eu[j] = *(const float4*)(eup + l * 16 + j * 4);

    float part = 0.f;
    const int* nv = neg_v + (size_t)b * K_NEG + wv * 8;

    #pragma unroll
    for (int it = 0; it < 2; ++it) {
        int ix = nv[it * 4 + g];
        const float* rp = (ix < NR) ? v_emb + (size_t)ix * D_DIM
                                    : tab_c + (size_t)(ix - NR) * D_DIM;
        float d = 0.f;
        #pragma unroll
        for (int j = 0; j < 4; ++j)
            d += dot4(eu[j], *(const float4*)(rp + l * 16 + j * 4));
        #pragma unroll
        for (int o = 1; o < 16; o <<= 1) d += __shfl_xor(d, o, 64);
        part -= logsig_fast(-clip10(d));
    }

    if (wv == 0) {
        int pv = pos_v[b];
        const float* rp = (pv < NR) ? v_emb + (size_t)pv * D_DIM
                                    : tab_c + (size_t)(pv - NR) * D_DIM;
        float d = 0.f;
        #pragma unroll
        for (int j = 0; j < 4; ++j)
            d += dot4(eu[j], *(const float4*)(rp + l * 16 + j * 4));
        #pragma unroll
        for (int o = 1; o < 16; o <<= 1) d += __shfl_xor(d, o, 64);
        float term = -logsig_fast(clip10(d));
        if (g == 0) part += term;
    }

    float ws = part;
    #pragma unroll
    for (int o = 32; o; o >>= 1) ws += __shfl_xor(ws, o, 64);
    __shared__ float sp[4];
    if (lane == 0) sp[wv] = ws * 0.0625f;
    __syncthreads();
    if (threadIdx.x == 0)
        partials[b] = sp[0] + sp[1] + sp[2] + sp[3];
}

__global__ __launch_bounds__(256) void reduce_kernel(
    const float* __restrict__ partials, float* __restrict__ out)
{
    float s = 0.f;
    for (int i = threadIdx.x; i < B_SIZE; i += 256) s += partials[i];
    #pragma unroll
    for (int o = 32; o; o >>= 1) s += __shfl_xor(s, o, 64);
    __shared__ float sp[4];
    if ((threadIdx.x & 63) == 0) sp[threadIdx.x >> 6] = s;
    __syncthreads();
    if (threadIdx.x == 0)
        out[0] = (sp[0] + sp[1] + sp[2] + sp[3]) * (2.0f / (float)B_SIZE);
}

// ---------------------------------------------------------------------------
extern "C" void kernel_launch(void* const* d_in, const int* in_sizes, int n_in,
                              void* d_out, int out_size, void* d_ws, size_t ws_size,
                              hipStream_t stream) {
    const int*   pos_u  = (const int*)  d_in[0];
    const int*   pos_v  = (const int*)  d_in[1];
    const int*   neg_v  = (const int*)  d_in[2];
    const float* u_emb  = (const float*)d_in[3];
    const float* v_emb  = (const float*)d_in[4];
    const float* stoich = (const float*)d_in[5];
    const float* tw1    = (const float*)d_in[6];
    const float* tb1    = (const float*)d_in[7];
    const float* tw2    = (const float*)d_in[8];
    const float* tb2    = (const float*)d_in[9];
    const float* cw1    = (const float*)d_in[10];
    const float* cb1    = (const float*)d_in[11];
    const float* cw2    = (const float*)d_in[12];
    const float* cb2    = (const float*)d_in[13];
    float* out = (float*)d_out;

    // workspace layout (bytes, 16B aligned)
    char* ws = (char*)d_ws;
    short* Xbf   = (short*)(ws);                      // 40000*128*2 = 10,240,000
    short* Xu    = (short*)(ws + 10240000);           //  8192*128*2 =  2,097,152
    short* W1T_t = (short*)(ws + 12337152);           //   512*128*2 =    131,072
    short* W1T_c = (short*)(ws + 12468224);           //                 131,072
    short* W2T_t = (short*)(ws + 12599296);           //   256*512*2 =    262,144
    short* W2T_c = (short*)(ws + 12861440);           //                 262,144
    float* tab_c = (float*)(ws + 13123584);           // 40000*256*4 = 40,960,000
    float* Ubuf  = (float*)(ws + 54083584);           //  8192*256*4 =  8,388,608
    float* parts = (float*)(ws + 62472192);           //  8192*4
    dim3 blk(256);

    // merged prep (1 launch)
    prep_kernel<<<dim3((N_CONV + N_XU + N_TR) / 256), blk, 0, stream>>>(
        stoich, pos_u, tw1, cw1, tw2, cw2,
        Xbf, Xu, W1T_t, W1T_c, W2T_t, W2T_c);

    // both fused MLP passes in one launch (c-side: 1250 blocks, u-side: 256)
    fused_mlp_kernel<<<dim3(CBLK + UBLK), blk, 0, stream>>>(
        Xbf, W1T_c, cb1, W2T_c, cb2, tab_c,
        Xu,  W1T_t, tb1, W2T_t, tb2, Ubuf);

    // scoring
    score_kernel<<<dim3(B_SIZE), blk, 0, stream>>>(pos_u, pos_v, neg_v,
                                                   u_emb, v_emb, tab_c, Ubuf, parts);
    reduce_kernel<<<dim3(1), blk, 0, stream>>>(parts, out);
}

// Round 3
// 292.771 us; speedup vs baseline: 1.1636x; 1.1636x over previous
//
#include <hip/hip_runtime.h>
#include <hip/hip_bf16.h>
#include <math.h>

// Problem constants (match reference)
#define V_SIZE 100000
#define D_DIM  256
#define S_DIM  128
#define H_DIM  512
#define B_SIZE 8192
#define K_NEG  32
#define NR     60000           // NUM_REGULAR
#define NMOD   (V_SIZE - NR)   // 40000 modified words

// MLP tiling (TM=48 was 60us; TM=32 regressed to 80us -> reverted)
#define TM     48              // rows per block (3 x 16)
#define CBLK   834             // ceil(40000/48)
#define UBLK   171             // ceil(8192/48)
#define MC_PAD (CBLK * TM)     // 40032 padded c-side rows
#define MU_PAD (UBLK * TM)     // 8208  padded u-side rows
// LDS H row stride (shorts). 516: layer-1 b16 writes land 2 lanes/bank
// (free); 1032-B rows keep 8-B alignment for ds_read_b64 in layer 2.
#define HPAD   516

typedef __attribute__((ext_vector_type(8))) short bf16x8;   // 8 bf16 = 4 VGPRs
typedef __attribute__((ext_vector_type(4))) float f32x4;

static __device__ __forceinline__ short f2bf(float f) {
    unsigned u = __builtin_bit_cast(unsigned, f);
    unsigned r = (u + 0x7fffu + ((u >> 16) & 1u)) >> 16;   // RNE
    return (short)r;
}

// ---------------------------------------------------------------------------
// Merged prep. NOW WRITES FRAGMENT-LINEAR LAYOUTS so every MFMA fragment
// load in fused_mlp is one contiguous 1KB wave-load (base + lane*8):
//   A-side (Xc/Xu):  elem((rt*4  + ks)*64 + lane)*8+j = X[rt*16+(lane&15)][ks*32+(lane>>4)*8+j]
//   W1 (4 ks-steps): elem((ks*32 + nt)*64 + lane)*8+j = w1[ks*32+(lane>>4)*8+j][nt*16+(lane&15)]
//   W2 (16 ks-steps):elem((ks*16 + nt)*64 + lane)*8+j = w2[...][...]
// Grid partition exact: N_CONV + N_XU short4-threads, then N_TR elem-threads.
// (1281024 + 262656 + 393216) / 256 = 7566 blocks.
// ---------------------------------------------------------------------------
#define N_CONV (MC_PAD * S_DIM / 4)           // 1,281,024
#define N_XU   (MU_PAD * S_DIM / 4)           //   262,656
#define N_TR   393216

__global__ __launch_bounds__(256) void prep_kernel(
    const float* __restrict__ stoich, const int* __restrict__ pos_u,
    const float* __restrict__ tw1, const float* __restrict__ cw1,
    const float* __restrict__ tw2, const float* __restrict__ cw2,
    short* __restrict__ xc, short* __restrict__ xu,
    short* __restrict__ W1T_t, short* __restrict__ W1T_c,
    short* __restrict__ W2T_t, short* __restrict__ W2T_c)
{
    int t = blockIdx.x * 256 + threadIdx.x;
    if (t < N_CONV + N_XU) {
        // A-side fragment-linear bf16 (short4 per thread, j0 in {0,4})
        const bool cside = t < N_CONV;
        const int e    = (cside ? t : t - N_CONV) * 4;
        const int j0   = e & 7;
        const int lane = (e >> 3) & 63;
        const int ks   = (e >> 9) & 3;
        const int rt   = e >> 11;
        const int row  = rt * 16 + (lane & 15);
        const int k    = ks * 32 + (lane >> 4) * 8 + j0;
        short4 o = {0, 0, 0, 0};
        if (cside) {
            if (row < NMOD) {
                const float4 v = *(const float4*)(stoich + (size_t)(NR + row) * S_DIM + k);
                o.x = f2bf(v.x); o.y = f2bf(v.y); o.z = f2bf(v.z); o.w = f2bf(v.w);
            }
            ((short4*)xc)[t] = o;
        } else {
            if (row < B_SIZE) {
                int pu = pos_u[row];
                const float4 v = *(const float4*)(stoich + (size_t)pu * S_DIM + k);
                o.x = f2bf(v.x); o.y = f2bf(v.y); o.z = f2bf(v.z); o.w = f2bf(v.w);
            }
            ((short4*)xu)[t - N_CONV] = o;
        }
    } else {
        int t3 = t - (N_CONV + N_XU);                 // [0, 393216)
        if (t3 < 131072) {                            // W1 pair (65536 each)
            const float* src = (t3 < 65536) ? tw1 : cw1;
            short*       dst = (t3 < 65536) ? W1T_t : W1T_c;
            int t4 = t3 & 65535;
            int j = t4 & 7, lane = (t4 >> 3) & 63;
            int nt = (t4 >> 9) & 31, ks = (t4 >> 14) & 3;
            int k = ks * 32 + (lane >> 4) * 8 + j, n = nt * 16 + (lane & 15);
            dst[t4] = f2bf(src[(size_t)k * H_DIM + n]);
        } else {                                      // W2 pair (131072 each)
            int t5 = t3 - 131072;
            const float* src = (t5 < 131072) ? tw2 : cw2;
            short*       dst = (t5 < 131072) ? W2T_t : W2T_c;
            int t4 = t5 & 131071;
            int j = t4 & 7, lane = (t4 >> 3) & 63;
            int nt = (t4 >> 9) & 15, ks = (t4 >> 13) & 15;
            int k = ks * 32 + (lane >> 4) * 8 + j, n = nt * 16 + (lane & 15);
            dst[t4] = f2bf(src[(size_t)k * D_DIM + n]);
        }
    }
}

// ---------------------------------------------------------------------------
// Fused 2-layer MLP (c-side table + u-side gathered rows in one launch).
// out[M][256] fp32 = relu(A[M][128] @ W1 + b1) @ W2 + b2
// Block = 4 waves, TM=48 rows. All global fragment loads are coalesced
// (fragment-linear layouts from prep). Layer 2: depth-3 register prefetch
// on W2 fragments, first 3 issued BEFORE the barrier (no LDS dependence)
// so they fly under the layer-1 epilogue. LDS A fragments depth-1.
// Verified MFMA layouts (m89/m91): A[m=lane&15][k=q*8+j]; B^T row (lane&15)
// supplies B[k][n=lane&15]; D: col=lane&15, row=q*4+reg.
// ---------------------------------------------------------------------------
__global__ __launch_bounds__(256, 3) void fused_mlp_kernel(
    const short* __restrict__ Xc,  const short* __restrict__ W1c,
    const float* __restrict__ b1c, const short* __restrict__ W2c,
    const float* __restrict__ b2c, float* __restrict__ outc,
    const short* __restrict__ Xu,  const short* __restrict__ W1u,
    const float* __restrict__ b1u, const short* __restrict__ W2u,
    const float* __restrict__ b2u, float* __restrict__ outu)
{
    __shared__ short sH[TM * HPAD];   // 49,536 B -> 3 blocks/CU

    const int blk = blockIdx.x;
    const short *A, *W1T, *W2T; const float *b1, *b2; float* out;
    int m0, rtb;
    if (blk < CBLK) { A = Xc; W1T = W1c; b1 = b1c; W2T = W2c; b2 = b2c;
                      out = outc; m0 = blk * TM; rtb = blk * 3; }
    else            { A = Xu; W1T = W1u; b1 = b1u; W2T = W2u; b2 = b2u;
                      out = outu; m0 = (blk - CBLK) * TM; rtb = (blk - CBLK) * 3; }

    const int lane = threadIdx.x & 63;
    const int wv   = threadIdx.x >> 6;
    const int fr   = lane & 15;
    const int q    = lane >> 4;

    // ---- layer 1 ----
    // A fragments: XF[((rtb+mi)*4 + ks)*512 + lane*8], contiguous per wave
    const short* Ap = A + (size_t)rtb * 2048 + lane * 8;
    bf16x8 af[4][3];
    #pragma unroll
    for (int ks = 0; ks < 4; ++ks)
        #pragma unroll
        for (int mi = 0; mi < 3; ++mi)
            af[ks][mi] = *(const bf16x8*)(Ap + mi * 2048 + ks * 512);

    #pragma unroll
    for (int half = 0; half < 2; ++half) {
        const int nt0 = wv * 8 + half * 4;            // n-tile base
        const short* Bp = W1T + (size_t)nt0 * 512 + lane * 8;
        f32x4 acc[3][4] = {};
        #pragma unroll
        for (int ks = 0; ks < 4; ++ks) {
            bf16x8 bfr[4];
            #pragma unroll
            for (int ni = 0; ni < 4; ++ni)
                bfr[ni] = *(const bf16x8*)(Bp + ks * 16384 + ni * 512);
            #pragma unroll
            for (int mi = 0; mi < 3; ++mi)
                #pragma unroll
                for (int ni = 0; ni < 4; ++ni)
                    acc[mi][ni] = __builtin_amdgcn_mfma_f32_16x16x32_bf16(
                        af[ks][mi], bfr[ni], acc[mi][ni], 0, 0, 0);
        }
        #pragma unroll
        for (int ni = 0; ni < 4; ++ni) {
            int c = (nt0 + ni) * 16 + fr;
            float bv = b1[c];
            #pragma unroll
            for (int mi = 0; mi < 3; ++mi)
                #pragma unroll
                for (int r = 0; r < 4; ++r)
                    sH[(mi * 16 + q * 4 + r) * HPAD + c] =
                        f2bf(fmaxf(acc[mi][ni][r] + bv, 0.f));
        }
    }

    // ---- layer 2: depth-3 global B prefetch (first 3 pre-barrier) ----
    // B fragments: W2F[((ks*16 + wv*4+ni)*64 + lane)*8]
    const short* Bp2 = W2T + (size_t)(wv * 4) * 512 + lane * 8;
    f32x4 acc2[3][4] = {};
    bf16x8 bA[4], bB[4], bC[4], bD[4], aA[3], aB[3];

    #define LOAD_B(ks, dst)                                                   \
        _Pragma("unroll")                                                     \
        for (int ni = 0; ni < 4; ++ni)                                        \
            dst[ni] = *(const bf16x8*)(Bp2 + (ks) * 8192 + ni * 512);
    #define LOAD_A(ks, dst)                                                   \
        _Pragma("unroll")                                                     \
        for (int mi = 0; mi < 3; ++mi) {                                      \
            const short* hp = &sH[(mi * 16 + fr) * HPAD + (ks) * 32 + q * 8]; \
            short4 lo = *(const short4*)hp;                                   \
            short4 hi = *(const short4*)(hp + 4);                             \
            bf16x8 v;                                                         \
            v[0] = lo.x; v[1] = lo.y; v[2] = lo.z; v[3] = lo.w;               \
            v[4] = hi.x; v[5] = hi.y; v[6] = hi.z; v[7] = hi.w;               \
            dst[mi] = v;                                                      \
        }

    LOAD_B(0, bA);
    LOAD_B(1, bB);
    LOAD_B(2, bC);
    __syncthreads();
    LOAD_A(0, aA);
    #pragma unroll
    for (int ks = 0; ks < 16; ++ks) {
        if (ks < 13) { LOAD_B(ks + 3, bD); }
        if (ks < 15) { LOAD_A(ks + 1, aB); }
        #pragma unroll
        for (int mi = 0; mi < 3; ++mi)
            #pragma unroll
            for (int ni = 0; ni < 4; ++ni)
                acc2[mi][ni] = __builtin_amdgcn_mfma_f32_16x16x32_bf16(
                    aA[mi], bA[ni], acc2[mi][ni], 0, 0, 0);
        if (ks < 15) {
            #pragma unroll
            for (int i = 0; i < 4; ++i) { bA[i] = bB[i]; bB[i] = bC[i]; bC[i] = bD[i]; }
            #pragma unroll
            for (int i = 0; i < 3; ++i) aA[i] = aB[i];
        }
    }
    #undef LOAD_A
    #undef LOAD_B

    #pragma unroll
    for (int ni = 0; ni < 4; ++ni) {
        int c = wv * 64 + ni * 16 + fr;
        float bv = b2[c];
        #pragma unroll
        for (int mi = 0; mi < 3; ++mi)
            #pragma unroll
            for (int r = 0; r < 4; ++r) {
                int row = m0 + mi * 16 + q * 4 + r;
                out[(size_t)row * D_DIM + c] = acc2[mi][ni][r] + bv;
            }
    }
}

// ---------------------------------------------------------------------------
// Scoring. One block (4 waves) per sample, 16-lane dots (4 rows in flight
// per wave), fast transcendental logsig.
// total_b = 2*( -logsig(clip(eu.ev)) - sum_k logsig(-clip(env_k.eu)) )
// ---------------------------------------------------------------------------
__device__ __forceinline__ float logsig_fast(float x) {
    float t = __expf(-fabsf(x));
    return fminf(x, 0.f) - __logf(1.f + t);
}
__device__ __forceinline__ float clip10(float x) {
    return fminf(fmaxf(x, -10.f), 10.f);
}
__device__ __forceinline__ float dot4(float4 a, float4 b) {
    return a.x * b.x + a.y * b.y + a.z * b.z + a.w * b.w;
}

__global__ __launch_bounds__(256) void score_kernel(
    const int*   __restrict__ pos_u,
    const int*   __restrict__ pos_v,
    const int*   __restrict__ neg_v,
    const float* __restrict__ u_emb,
    const float* __restrict__ v_emb,
    const float* __restrict__ tab_c,   // [MC_PAD][256] fp32
    const float* __restrict__ Ubuf,    // [MU_PAD][256] fp32
    float* __restrict__ partials)      // [B]
{
    const int b    = blockIdx.x;
    const int lane = threadIdx.x & 63;
    const int wv   = threadIdx.x >> 6;
    const int g    = lane >> 4;
    const int l    = lane & 15;

    int pu = pos_u[b];
    const float* eup = (pu < NR) ? u_emb + (size_t)pu * D_DIM
                                 : Ubuf  + (size_t)b  * D_DIM;
    float4 eu[4];
    #pragma unroll
    for (int j = 0; j < 4; ++j)
        eu[j] = *(const float4*)(eup + l * 16 + j * 4);

    float part = 0.f;
    const int* nv = neg_v + (size_t)b * K_NEG + wv * 8;

    #pragma unroll
    for (int it = 0; it < 2; ++it) {
        int ix = nv[it * 4 + g];
        const float* rp = (ix < NR) ? v_emb + (size_t)ix * D_DIM
                                    : tab_c + (size_t)(ix - NR) * D_DIM;
        float d = 0.f;
        #pragma unroll
        for (int j = 0; j < 4; ++j)
            d += dot4(eu[j], *(const float4*)(rp + l * 16 + j * 4));
        #pragma unroll
        for (int o = 1; o < 16; o <<= 1) d += __shfl_xor(d, o, 64);
        part -= logsig_fast(-clip10(d));
    }

    if (wv == 0) {
        int pv = pos_v[b];
        const float* rp = (pv < NR) ? v_emb + (size_t)pv * D_DIM
                                    : tab_c + (size_t)(pv - NR) * D_DIM;
        float d = 0.f;
        #pragma unroll
        for (int j = 0; j < 4; ++j)
            d += dot4(eu[j], *(const float4*)(rp + l * 16 + j * 4));
        #pragma unroll
        for (int o = 1; o < 16; o <<= 1) d += __shfl_xor(d, o, 64);
        float term = -logsig_fast(clip10(d));
        if (g == 0) part += term;
    }

    float ws = part;
    #pragma unroll
    for (int o = 32; o; o >>= 1) ws += __shfl_xor(ws, o, 64);
    __shared__ float sp[4];
    if (lane == 0) sp[wv] = ws * 0.0625f;
    __syncthreads();
    if (threadIdx.x == 0)
        partials[b] = sp[0] + sp[1] + sp[2] + sp[3];
}

__global__ __launch_bounds__(256) void reduce_kernel(
    const float* __restrict__ partials, float* __restrict__ out)
{
    float s = 0.f;
    for (int i = threadIdx.x; i < B_SIZE; i += 256) s += partials[i];
    #pragma unroll
    for (int o = 32; o; o >>= 1) s += __shfl_xor(s, o, 64);
    __shared__ float sp[4];
    if ((threadIdx.x & 63) == 0) sp[threadIdx.x >> 6] = s;
    __syncthreads();
    if (threadIdx.x == 0)
        out[0] = (sp[0] + sp[1] + sp[2] + sp[3]) * (2.0f / (float)B_SIZE);
}

// ---------------------------------------------------------------------------
extern "C" void kernel_launch(void* const* d_in, const int* in_sizes, int n_in,
                              void* d_out, int out_size, void* d_ws, size_t ws_size,
                              hipStream_t stream) {
    const int*   pos_u  = (const int*)  d_in[0];
    const int*   pos_v  = (const int*)  d_in[1];
    const int*   neg_v  = (const int*)  d_in[2];
    const float* u_emb  = (const float*)d_in[3];
    const float* v_emb  = (const float*)d_in[4];
    const float* stoich = (const float*)d_in[5];
    const float* tw1    = (const float*)d_in[6];
    const float* tb1    = (const float*)d_in[7];
    const float* tw2    = (const float*)d_in[8];
    const float* tb2    = (const float*)d_in[9];
    const float* cw1    = (const float*)d_in[10];
    const float* cb1    = (const float*)d_in[11];
    const float* cw2    = (const float*)d_in[12];
    const float* cb2    = (const float*)d_in[13];
    float* out = (float*)d_out;

    // workspace layout (bytes, 16B aligned)
    char* ws = (char*)d_ws;
    short* Xbf   = (short*)(ws);                      // MC_PAD*128*2 = 10,248,192
    short* Xu    = (short*)(ws + 10248192);           // MU_PAD*128*2 =  2,101,248
    short* W1T_t = (short*)(ws + 12349440);           //   512*128*2  =    131,072
    short* W1T_c = (short*)(ws + 12480512);           //                  131,072
    short* W2T_t = (short*)(ws + 12611584);           //   256*512*2  =    262,144
    short* W2T_c = (short*)(ws + 12873728);           //                  262,144
    float* tab_c = (float*)(ws + 13135872);           // MC_PAD*256*4 = 40,992,768
    float* Ubuf  = (float*)(ws + 54128640);           // MU_PAD*256*4 =  8,404,992
    float* parts = (float*)(ws + 62533632);           //  8192*4

    dim3 blk(256);

    // merged prep (1 launch)
    prep_kernel<<<dim3((N_CONV + N_XU + N_TR) / 256), blk, 0, stream>>>(
        stoich, pos_u, tw1, cw1, tw2, cw2,
        Xbf, Xu, W1T_t, W1T_c, W2T_t, W2T_c);

    // both fused MLP passes in one launch (c-side: 834 blocks, u-side: 171)
    fused_mlp_kernel<<<dim3(CBLK + UBLK), blk, 0, stream>>>(
        Xbf, W1T_c, cb1, W2T_c, cb2, tab_c,
        Xu,  W1T_t, tb1, W2T_t, tb2, Ubuf);

    // scoring
    score_kernel<<<dim3(B_SIZE), blk, 0, stream>>>(pos_u, pos_v, neg_v,
                                                   u_emb, v_emb, tab_c, Ubuf, parts);
    reduce_kernel<<<dim3(1), blk, 0, stream>>>(parts, out);
}

// Round 5
// 290.782 us; speedup vs baseline: 1.1715x; 1.0068x over previous
//
#include <hip/hip_runtime.h>
#include <hip/hip_bf16.h>
#include <math.h>

// Problem constants (match reference)
#define V_SIZE 100000
#define D_DIM  256
#define S_DIM  128
#define H_DIM  512
#define B_SIZE 8192
#define K_NEG  32
#define NR     60000           // NUM_REGULAR
#define NMOD   (V_SIZE - NR)   // 40000 modified words

// MLP tiling (TM=48 = 60us baseline; TM=32 regressed to 80us -> keep 48)
#define TM     48              // rows per block (3 x 16)
#define CBLK   834             // ceil(40000/48)
#define UBLK   171             // ceil(8192/48)
#define MC_PAD (CBLK * TM)     // 40032 padded c-side rows
#define MU_PAD (UBLK * TM)     // 8208  padded u-side rows
// LDS H row stride (shorts). 516: layer-1 b16 writes land 2 lanes/bank
// (free); 1032-B rows keep 8-B alignment for ds_read_b64 in layer 2.
#define HPAD   516

typedef __attribute__((ext_vector_type(8))) short bf16x8;   // 8 bf16 = 4 VGPRs
typedef __attribute__((ext_vector_type(8))) unsigned short u16x8;
typedef __attribute__((ext_vector_type(4))) float f32x4;

static __device__ __forceinline__ short f2bf(float f) {
    unsigned u = __builtin_bit_cast(unsigned, f);
    unsigned r = (u + 0x7fffu + ((u >> 16) & 1u)) >> 16;   // RNE
    return (short)r;
}
static __device__ __forceinline__ float bf2f(unsigned short h) {
    return __builtin_bit_cast(float, ((unsigned)h) << 16);
}

// ---------------------------------------------------------------------------
// tab_c / Ubuf STORAGE LAYOUT (bf16, permuted columns):
//   storage position p = wv*64 + fr*4 + ni   <->   logical col c = wv*64 + ni*16 + fr
// (wv 0..3, fr 0..15, ni 0..3). Dot products are permutation-invariant; the
// fused epilogue writes short4 (contiguous in p), score reads bf16 rows
// contiguously and fp32 rows (v_emb/u_emb, logical layout) as 4 x float4
// with the register pairing fixed at compile time.
// ---------------------------------------------------------------------------

// ---------------------------------------------------------------------------
// Merged prep. Fragment-linear layouts so every MFMA fragment load in
// fused_mlp is one contiguous 1KB wave-load (base + lane*8):
//   A-side (Xc/Xu):  elem((rt*4  + ks)*64 + lane)*8+j = X[rt*16+(lane&15)][ks*32+(lane>>4)*8+j]
//   W1 (4 ks-steps): elem((ks*32 + nt)*64 + lane)*8+j = w1[ks*32+(lane>>4)*8+j][nt*16+(lane&15)]
//   W2 (16 ks-steps):elem((ks*16 + nt)*64 + lane)*8+j = w2[...][...]
// (1281024 + 262656 + 393216) / 256 = 7566 blocks exactly.
// ---------------------------------------------------------------------------
#define N_CONV (MC_PAD * S_DIM / 4)           // 1,281,024
#define N_XU   (MU_PAD * S_DIM / 4)           //   262,656
#define N_TR   393216

__global__ __launch_bounds__(256) void prep_kernel(
    const float* __restrict__ stoich, const int* __restrict__ pos_u,
    const float* __restrict__ tw1, const float* __restrict__ cw1,
    const float* __restrict__ tw2, const float* __restrict__ cw2,
    short* __restrict__ xc, short* __restrict__ xu,
    short* __restrict__ W1T_t, short* __restrict__ W1T_c,
    short* __restrict__ W2T_t, short* __restrict__ W2T_c)
{
    int t = blockIdx.x * 256 + threadIdx.x;
    if (t < N_CONV + N_XU) {
        // A-side fragment-linear bf16 (short4 per thread, j0 in {0,4})
        const bool cside = t < N_CONV;
        const int e    = (cside ? t : t - N_CONV) * 4;
        const int j0   = e & 7;
        const int lane = (e >> 3) & 63;
        const int ks   = (e >> 9) & 3;
        const int rt   = e >> 11;
        const int row  = rt * 16 + (lane & 15);
        const int k    = ks * 32 + (lane >> 4) * 8 + j0;
        short4 o = {0, 0, 0, 0};
        if (cside) {
            if (row < NMOD) {
                const float4 v = *(const float4*)(stoich + (size_t)(NR + row) * S_DIM + k);
                o.x = f2bf(v.x); o.y = f2bf(v.y); o.z = f2bf(v.z); o.w = f2bf(v.w);
            }
            ((short4*)xc)[t] = o;
        } else {
            if (row < B_SIZE) {
                int pu = pos_u[row];
                const float4 v = *(const float4*)(stoich + (size_t)pu * S_DIM + k);
                o.x = f2bf(v.x); o.y = f2bf(v.y); o.z = f2bf(v.z); o.w = f2bf(v.w);
            }
            ((short4*)xu)[t - N_CONV] = o;
        }
    } else {
        int t3 = t - (N_CONV + N_XU);                 // [0, 393216)
        if (t3 < 131072) {                            // W1 pair (65536 each)
            const float* src = (t3 < 65536) ? tw1 : cw1;
            short*       dst = (t3 < 65536) ? W1T_t : W1T_c;
            int t4 = t3 & 65535;
            int j = t4 & 7, lane = (t4 >> 3) & 63;
            int nt = (t4 >> 9) & 31, ks = (t4 >> 14) & 3;
            int k = ks * 32 + (lane >> 4) * 8 + j, n = nt * 16 + (lane & 15);
            dst[t4] = f2bf(src[(size_t)k * H_DIM + n]);
        } else {                                      // W2 pair (131072 each)
            int t5 = t3 - 131072;
            const float* src = (t5 < 131072) ? tw2 : cw2;
            short*       dst = (t5 < 131072) ? W2T_t : W2T_c;
            int t4 = t5 & 131071;
            int j = t4 & 7, lane = (t4 >> 3) & 63;
            int nt = (t4 >> 9) & 15, ks = (t4 >> 13) & 15;
            int k = ks * 32 + (lane >> 4) * 8 + j, n = nt * 16 + (lane & 15);
            dst[t4] = f2bf(src[(size_t)k * D_DIM + n]);
        }
    }
}

// ---------------------------------------------------------------------------
// Fused 2-layer MLP (c-side table + u-side gathered rows in one launch).
// outF[M][256] bf16 (permuted storage) = relu(A[M][128] @ W1 + b1) @ W2 + b2
// Block = 4 waves, TM=48 rows. All global fragment loads coalesced
// (fragment-linear layouts from prep). Layer 2: depth-3 register prefetch
// on W2 fragments, first 3 issued BEFORE the barrier. Epilogue: short4
// stores in permuted storage order (12 x 8B per lane vs 48 scalar dwords).
// Verified MFMA layouts (m89/m91): A[m=lane&15][k=q*8+j]; B^T row (lane&15)
// supplies B[k][n=lane&15]; D: col=lane&15, row=q*4+reg.
// ---------------------------------------------------------------------------
__global__ __launch_bounds__(256, 3) void fused_mlp_kernel(
    const short* __restrict__ Xc,  const short* __restrict__ W1c,
    const float* __restrict__ b1c, const short* __restrict__ W2c,
    const float* __restrict__ b2c, short* __restrict__ outc,
    const short* __restrict__ Xu,  const short* __restrict__ W1u,
    const float* __restrict__ b1u, const short* __restrict__ W2u,
    const float* __restrict__ b2u, short* __restrict__ outu)
{
    __shared__ short sH[TM * HPAD];   // 49,536 B -> 3 blocks/CU

    const int blk = blockIdx.x;
    const short *A, *W1T, *W2T; const float *b1, *b2; short* out;
    int m0, rtb;
    if (blk < CBLK) { A = Xc; W1T = W1c; b1 = b1c; W2T = W2c; b2 = b2c;
                      out = outc; m0 = blk * TM; rtb = blk * 3; }
    else            { A = Xu; W1T = W1u; b1 = b1u; W2T = W2u; b2 = b2u;
                      out = outu; m0 = (blk - CBLK) * TM; rtb = (blk - CBLK) * 3; }

    const int lane = threadIdx.x & 63;
    const int wv   = threadIdx.x >> 6;
    const int fr   = lane & 15;
    const int q    = lane >> 4;

    // ---- layer 1 ----
    // A fragments: XF[((rtb+mi)*4 + ks)*512 + lane*8], contiguous per wave
    const short* Ap = A + (size_t)rtb * 2048 + lane * 8;
    bf16x8 af[4][3];
    #pragma unroll
    for (int ks = 0; ks < 4; ++ks)
        #pragma unroll
        for (int mi = 0; mi < 3; ++mi)
            af[ks][mi] = *(const bf16x8*)(Ap + mi * 2048 + ks * 512);

    #pragma unroll
    for (int half = 0; half < 2; ++half) {
        const int nt0 = wv * 8 + half * 4;            // n-tile base
        const short* Bp = W1T + (size_t)nt0 * 512 + lane * 8;
        f32x4 acc[3][4] = {};
        #pragma unroll
        for (int ks = 0; ks < 4; ++ks) {
            bf16x8 bfr[4];
            #pragma unroll
            for (int ni = 0; ni < 4; ++ni)
                bfr[ni] = *(const bf16x8*)(Bp + ks * 16384 + ni * 512);
            #pragma unroll
            for (int mi = 0; mi < 3; ++mi)
                #pragma unroll
                for (int ni = 0; ni < 4; ++ni)
                    acc[mi][ni] = __builtin_amdgcn_mfma_f32_16x16x32_bf16(
                        af[ks][mi], bfr[ni], acc[mi][ni], 0, 0, 0);
        }
        #pragma unroll
        for (int ni = 0; ni < 4; ++ni) {
            int c = (nt0 + ni) * 16 + fr;
            float bv = b1[c];
            #pragma unroll
            for (int mi = 0; mi < 3; ++mi)
                #pragma unroll
                for (int r = 0; r < 4; ++r)
                    sH[(mi * 16 + q * 4 + r) * HPAD + c] =
                        f2bf(fmaxf(acc[mi][ni][r] + bv, 0.f));
        }
    }

    // ---- layer 2: depth-3 global B prefetch (first 3 pre-barrier) ----
    // B fragments: W2F[((ks*16 + wv*4+ni)*64 + lane)*8]
    const short* Bp2 = W2T + (size_t)(wv * 4) * 512 + lane * 8;
    f32x4 acc2[3][4] = {};
    bf16x8 bA[4], bB[4], bC[4], bD[4], aA[3], aB[3];

    #define LOAD_B(ks, dst)                                                   \
        _Pragma("unroll")                                                     \
        for (int ni = 0; ni < 4; ++ni)                                        \
            dst[ni] = *(const bf16x8*)(Bp2 + (ks) * 8192 + ni * 512);
    #define LOAD_A(ks, dst)                                                   \
        _Pragma("unroll")                                                     \
        for (int mi = 0; mi < 3; ++mi) {                                      \
            const short* hp = &sH[(mi * 16 + fr) * HPAD + (ks) * 32 + q * 8]; \
            short4 lo = *(const short4*)hp;                                   \
            short4 hi = *(const short4*)(hp + 4);                             \
            bf16x8 v;                                                         \
            v[0] = lo.x; v[1] = lo.y; v[2] = lo.z; v[3] = lo.w;               \
            v[4] = hi.x; v[5] = hi.y; v[6] = hi.z; v[7] = hi.w;               \
            dst[mi] = v;                                                      \
        }

    LOAD_B(0, bA);
    LOAD_B(1, bB);
    LOAD_B(2, bC);
    __syncthreads();
    LOAD_A(0, aA);
    #pragma unroll
    for (int ks = 0; ks < 16; ++ks) {
        if (ks < 13) { LOAD_B(ks + 3, bD); }
        if (ks < 15) { LOAD_A(ks + 1, aB); }
        #pragma unroll
        for (int mi = 0; mi < 3; ++mi)
            #pragma unroll
            for (int ni = 0; ni < 4; ++ni)
                acc2[mi][ni] = __builtin_amdgcn_mfma_f32_16x16x32_bf16(
                    aA[mi], bA[ni], acc2[mi][ni], 0, 0, 0);
        if (ks < 15) {
            #pragma unroll
            for (int i = 0; i < 4; ++i) { bA[i] = bB[i]; bB[i] = bC[i]; bC[i] = bD[i]; }
            #pragma unroll
            for (int i = 0; i < 3; ++i) aA[i] = aB[i];
        }
    }
    #undef LOAD_A
    #undef LOAD_B

    // epilogue: bf16 short4 stores in permuted storage order
    float bv[4];
    #pragma unroll
    for (int ni = 0; ni < 4; ++ni)
        bv[ni] = b2[wv * 64 + ni * 16 + fr];
    #pragma unroll
    for (int mi = 0; mi < 3; ++mi)
        #pragma unroll
        for (int r = 0; r < 4; ++r) {
            int row = m0 + mi * 16 + q * 4 + r;
            short4 s;
            s.x = f2bf(acc2[mi][0][r] + bv[0]);
            s.y = f2bf(acc2[mi][1][r] + bv[1]);
            s.z = f2bf(acc2[mi][2][r] + bv[2]);
            s.w = f2bf(acc2[mi][3][r] + bv[3]);
            *(short4*)(out + (size_t)row * D_DIM + wv * 64 + fr * 4) = s;
        }
}

// ---------------------------------------------------------------------------
// Scoring. One block (4 waves) per sample; each wave holds 4 rows in flight
// (16-lane dots). fp32 rows (u_emb/v_emb, logical layout) are read as
// 4 x float4 in storage order; bf16 rows (tab/Ubuf) contiguous. Register
// index i = j*4 + ni pairs euf[i] with row storage position p = l*16 + i.
// total_b = 2*( -logsig(clip(eu.ev)) - sum_k logsig(-clip(env_k.eu)) )
// ---------------------------------------------------------------------------
__device__ __forceinline__ float logsig_fast(float x) {
    float t = __expf(-fabsf(x));
    return fminf(x, 0.f) - __logf(1.f + t);
}
__device__ __forceinline__ float clip10(float x) {
    return fminf(fmaxf(x, -10.f), 10.f);
}

__global__ __launch_bounds__(256) void score_kernel(
    const int*   __restrict__ pos_u,
    const int*   __restrict__ pos_v,
    const int*   __restrict__ neg_v,
    const float* __restrict__ u_emb,
    const float* __restrict__ v_emb,
    const unsigned short* __restrict__ tab_c,   // [MC_PAD][256] bf16, permuted
    const unsigned short* __restrict__ Ubuf,    // [MU_PAD][256] bf16, permuted
    float* __restrict__ partials)               // [B]
{
    const int b    = blockIdx.x;
    const int lane = threadIdx.x & 63;
    const int wv   = threadIdx.x >> 6;
    const int g    = lane >> 4;
    const int l    = lane & 15;
    const int w64  = (l >> 2) * 64;        // storage 64-col block
    const int s4   = (l & 3) * 4;          // fr base within block

    // euf[i], i = j*4 + ni  <->  logical col w64 + ni*16 + s4 + j
    float euf[16];
    int pu = pos_u[b];
    if (pu < NR) {
        const float* eup = u_emb + (size_t)pu * D_DIM;
        #pragma unroll
        for (int n = 0; n < 4; ++n) {
            float4 v = *(const float4*)(eup + w64 + n * 16 + s4);
            euf[0 + n] = v.x; euf[4 + n] = v.y; euf[8 + n] = v.z; euf[12 + n] = v.w;
        }
    } else {
        const unsigned short* eup = Ubuf + (size_t)b * D_DIM + l * 16;
        u16x8 h0 = *(const u16x8*)eup;
        u16x8 h1 = *(const u16x8*)(eup + 8);
        #pragma unroll
        for (int i = 0; i < 8; ++i) { euf[i] = bf2f(h0[i]); euf[8 + i] = bf2f(h1[i]); }
    }

    float part = 0.f;
    const int* nv = neg_v + (size_t)b * K_NEG + wv * 8;

    #pragma unroll
    for (int it = 0; it < 3; ++it) {
        int ix;
        if (it < 2)            ix = nv[it * 4 + g];
        else if (wv == 0)      ix = pos_v[b];          // pos row on wave 0
        else                   break;
        float d = 0.f;
        if (ix < NR) {
            const float* rp = v_emb + (size_t)ix * D_DIM;
            #pragma unroll
            for (int n = 0; n < 4; ++n) {
                float4 v = *(const float4*)(rp + w64 + n * 16 + s4);
                d += euf[0 + n] * v.x + euf[4 + n] * v.y
                   + euf[8 + n] * v.z + euf[12 + n] * v.w;
            }
        } else {
            const unsigned short* rp = tab_c + (size_t)(ix - NR) * D_DIM + l * 16;
            u16x8 h0 = *(const u16x8*)rp;
            u16x8 h1 = *(const u16x8*)(rp + 8);
            #pragma unroll
            for (int i = 0; i < 8; ++i)
                d += euf[i] * bf2f(h0[i]) + euf[8 + i] * bf2f(h1[i]);
        }
        #pragma unroll
        for (int o = 1; o < 16; o <<= 1) d += __shfl_xor(d, o, 64);
        if (it < 2)        part -= logsig_fast(-clip10(d));
        else if (g == 0)   part -= logsig_fast( clip10(d));
    }

    float ws = part;
    #pragma unroll
    for (int o = 32; o; o >>= 1) ws += __shfl_xor(ws, o, 64);
    __shared__ float sp[4];
    if (lane == 0) sp[wv] = ws * 0.0625f;
    __syncthreads();
    if (threadIdx.x == 0)
        partials[b] = sp[0] + sp[1] + sp[2] + sp[3];
}

__global__ __launch_bounds__(256) void reduce_kernel(
    const float* __restrict__ partials, float* __restrict__ out)
{
    float s = 0.f;
    for (int i = threadIdx.x; i < B_SIZE; i += 256) s += partials[i];
    #pragma unroll
    for (int o = 32; o; o >>= 1) s += __shfl_xor(s, o, 64);
    __shared__ float sp[4];
    if ((threadIdx.x & 63) == 0) sp[threadIdx.x >> 6] = s;
    __syncthreads();
    if (threadIdx.x == 0)
        out[0] = (sp[0] + sp[1] + sp[2] + sp[3]) * (2.0f / (float)B_SIZE);
}

// ---------------------------------------------------------------------------
extern "C" void kernel_launch(void* const* d_in, const int* in_sizes, int n_in,
                              void* d_out, int out_size, void* d_ws, size_t ws_size,
                              hipStream_t stream) {
    const int*   pos_u  = (const int*)  d_in[0];
    const int*   pos_v  = (const int*)  d_in[1];
    const int*   neg_v  = (const int*)  d_in[2];
    const float* u_emb  = (const float*)d_in[3];
    const float* v_emb  = (const float*)d_in[4];
    const float* stoich = (const float*)d_in[5];
    const float* tw1    = (const float*)d_in[6];
    const float* tb1    = (const float*)d_in[7];
    const float* tw2    = (const float*)d_in[8];
    const float* tb2    = (const float*)d_in[9];
    const float* cw1    = (const float*)d_in[10];
    const float* cb1    = (const float*)d_in[11];
    const float* cw2    = (const float*)d_in[12];
    const float* cb2    = (const float*)d_in[13];
    float* out = (float*)d_out;

    // workspace layout (bytes, 16B aligned)
    char* ws = (char*)d_ws;
    short* Xbf   = (short*)(ws);                      // MC_PAD*128*2 = 10,248,192
    short* Xu    = (short*)(ws + 10248192);           // MU_PAD*128*2 =  2,101,248
    short* W1T_t = (short*)(ws + 12349440);           //   512*128*2  =    131,072
    short* W1T_c = (short*)(ws + 12480512);           //                  131,072
    short* W2T_t = (short*)(ws + 12611584);           //   256*512*2  =    262,144
    short* W2T_c = (short*)(ws + 12873728);           //                  262,144
    short* tab_c = (short*)(ws + 13135872);           // MC_PAD*256*2 = 20,496,384
    short* Ubuf  = (short*)(ws + 33632256);           // MU_PAD*256*2 =  4,202,496
    float* parts = (float*)(ws + 37834752);           //  8192*4

    dim3 blk(256);

    // merged prep (1 launch)
    prep_kernel<<<dim3((N_CONV + N_XU + N_TR) / 256), blk, 0, stream>>>(
        stoich, pos_u, tw1, cw1, tw2, cw2,
        Xbf, Xu, W1T_t, W1T_c, W2T_t, W2T_c);

    // both fused MLP passes in one launch (c-side: 834 blocks, u-side: 171)
    fused_mlp_kernel<<<dim3(CBLK + UBLK), blk, 0, stream>>>(
        Xbf, W1T_c, cb1, W2T_c, cb2, tab_c,
        Xu,  W1T_t, tb1, W2T_t, tb2, Ubuf);

    // scoring
    score_kernel<<<dim3(B_SIZE), blk, 0, stream>>>(
        pos_u, pos_v, neg_v, u_emb, v_emb,
        (const unsigned short*)tab_c, (const unsigned short*)Ubuf, parts);
    reduce_kernel<<<dim3(1), blk, 0, stream>>>(parts, out);
}